// Round 15
// baseline (174.958 us; speedup 1.0000x reference)
//
#include <hip/hip_runtime.h>
#include <hip/hip_bf16.h>

#define NUM_GRAPHS 64
#define NODES 256
#define EDGES 1024
#define NTOT (NUM_GRAPHS * NODES) /* 16384 */
#define DF 512
#define HF 1024
#define HP 256
#define NC 10
#define INF32 0xFFFFFFFFu

typedef short bf16x8 __attribute__((ext_vector_type(8)));
typedef float f32x4 __attribute__((ext_vector_type(4)));

__device__ __forceinline__ unsigned short bf16r(float f) {
    __hip_bfloat16 h = __float2bfloat16(f);
    return *(unsigned short*)&h;
}
// monotone order-preserving encode for fp32 (bijection, works for +/-)
__device__ __forceinline__ unsigned encf(float x) {
    union { float f; unsigned u; } c; c.f = x;
    return (c.u & 0x80000000u) ? ~c.u : (c.u | 0x80000000u);
}

// ---- w1 (f32 [k][j]) -> w1f bf16, LANE-ORDERED MFMA B-fragment layout ----
__global__ __launch_bounds__(256) void k_cvt_frag(
    const float* __restrict__ w1, unsigned short* __restrict__ w1f)
{
    __shared__ float ls[128 * 16];   // [kk][c], 8 KB
    const int tid = threadIdx.x;
    const int cg = blockIdx.x >> 2, kq = blockIdx.x & 3;
    const int c = tid & 15, kr = tid >> 4;
#pragma unroll
    for (int it = 0; it < 8; ++it) {
        int kk = it * 16 + kr;
        ls[kk * 16 + c] = w1[(size_t)(kq * 128 + kk) * HF + cg * 16 + c];
    }
    __syncthreads();
    const int tt = tid >> 6, n16 = tid & 15, q = (tid >> 4) & 3;
    unsigned short v[8];
#pragma unroll
    for (int j = 0; j < 8; ++j)
        v[j] = bf16r(ls[(tt * 32 + q * 8 + j) * 16 + n16]);
    size_t off = ((size_t)(cg * 16 + kq * 4 + tt) * 64 + (q * 16 + n16)) * 8;
#pragma unroll
    for (int j = 0; j < 8; ++j) w1f[off + j] = v[j];
}

// ------- Stage 1 (MFMA v9): zbuf = relu(x@W1+b1)@w2 quarter-partials -----
// v19: 1024 blocks (4/CU). Block b: rows (b>>2)*64, column quarter cq=b&3
// (16 cgs). All 4 waves share one cg pipeline: wave = 16-row tile computing
// all 16 cols of the current cg (A = 16 bf16x8 = 64 VGPR, one 16-MFMA
// chain/iter). LDS halves to 2x16KB double-buffer -> 4 blocks/CU (v17's
// 4x16KB capped at 2). 4 waves/SIMD overlap the longer dependent chain
// (m114). Fragment addressing unchanged (per-cg tile = t*512 + lane*8).
// Output: partial plane cq of zbuf[4][NTOT]; consumers sum 4 planes.
__global__ __launch_bounds__(256, 4) void k_fil_mfma(
    const float* __restrict__ x, const unsigned short* __restrict__ w1f,
    const float* __restrict__ b1, const float* __restrict__ w2,
    float* __restrict__ zbuf /* [4][NTOT] */)
{
    __shared__ unsigned short Bbuf[2 * 8192];  // 2 x 16 KB
    __shared__ float zpart[4][16];
    const int tid = threadIdx.x;
    const int lane = tid & 63;
    const int wv = tid >> 6;            // row 16-tile 0..3
    const int l15 = lane & 15, quad = lane >> 4;
    const int r0 = (blockIdx.x >> 2) * 64;
    const int cq = blockIdx.x & 3;      // column quarter
    const int cg0 = cq * 16;
    const int row = r0 + wv * 16 + l15;

    // A fragments for this wave's 16 rows over full K (f32 -> bf16 in regs)
    bf16x8 A[16];
#pragma unroll
    for (int t = 0; t < 16; ++t) {
        const float* s0 = x + (size_t)row * DF + t * 32 + quad * 8;
        float4 a = *(const float4*)s0, b = *(const float4*)(s0 + 4);
        A[t][0]=(short)bf16r(a.x); A[t][1]=(short)bf16r(a.y);
        A[t][2]=(short)bf16r(a.z); A[t][3]=(short)bf16r(a.w);
        A[t][4]=(short)bf16r(b.x); A[t][5]=(short)bf16r(b.y);
        A[t][6]=(short)bf16r(b.z); A[t][7]=(short)bf16r(b.w);
    }

    // stage cg0 into buffer 0 (16 KB: 1024 uint4, 4 per thread)
    {
        const uint4* s = (const uint4*)(w1f + (size_t)cg0 * 8192);
        uint4* d = (uint4*)Bbuf;
#pragma unroll
        for (int j = 0; j < 4; ++j) d[tid + j * 256] = s[tid + j * 256];
    }
    __syncthreads();

    float s_[4] = {0, 0, 0, 0};

    for (int i = 0; i < 16; ++i) {
        const int par = i & 1;
        uint4 pf[4];
        if (i < 15) {
            const uint4* s = (const uint4*)(w1f + (size_t)(cg0 + i + 1) * 8192);
#pragma unroll
            for (int j = 0; j < 4; ++j) pf[j] = s[tid + j * 256];
        }
        const unsigned short* bb = Bbuf + par * 8192 + lane * 8;
        f32x4 a0 = {0, 0, 0, 0};
#pragma unroll
        for (int t = 0; t < 16; ++t) {
            bf16x8 Bf = *(const bf16x8*)(bb + t * 512);
            a0 = __builtin_amdgcn_mfma_f32_16x16x32_bf16(A[t], Bf, a0, 0, 0, 0);
        }
        const int col = (cg0 + i) * 16 + l15;
        const float b1c = b1[col], w2c = w2[col];
#pragma unroll
        for (int r = 0; r < 4; ++r) {
            float h0 = a0[r] + b1c; h0 = h0 > 0.f ? h0 : 0.f;
            s_[r] = fmaf(h0, w2c, s_[r]);
        }
        if (i < 15) {
            uint4* d = (uint4*)Bbuf + (par ^ 1) * 1024;
#pragma unroll
            for (int j = 0; j < 4; ++j) d[tid + j * 256] = pf[j];
        }
        __syncthreads();
    }

    // reduce over 16 col-lanes; each wave publishes 16 row-partials
#pragma unroll
    for (int r = 0; r < 4; ++r) {
        float vv = s_[r];
        vv += __shfl_xor(vv, 1, 16);
        vv += __shfl_xor(vv, 2, 16);
        vv += __shfl_xor(vv, 4, 16);
        vv += __shfl_xor(vv, 8, 16);
        if (l15 == 0) zpart[wv][quad * 4 + r] = vv;
    }
    __syncthreads();
    if (tid < 64)
        zbuf[(size_t)cq * NTOT + r0 + tid] = zpart[tid >> 4][tid & 15];
}

// ---------------- Stage 1 legacy (fp32 VALU) — ws_size fallback -----------
#define TN2 16
__global__ __launch_bounds__(256) void k_fil(
    const float* __restrict__ x, const float* __restrict__ w1,
    const float* __restrict__ b1, const float* __restrict__ w2,
    float* __restrict__ zout)
{
    __shared__ float xs[TN2][DF];
    __shared__ float part[256];
    const int tid = threadIdx.x;
    const int n0 = blockIdx.x * TN2;
    for (int c = tid; c < TN2 * DF / 4; c += 256) {
        int n = c >> 7, k4 = (c & 127) << 2;
        *(float4*)&xs[n][k4] = *(const float4*)(x + (size_t)(n0 + n) * DF + k4);
    }
    __syncthreads();
    float h[TN2][4];
#pragma unroll
    for (int n = 0; n < TN2; ++n)
#pragma unroll
        for (int q = 0; q < 4; ++q) h[n][q] = 0.f;
    for (int k = 0; k < DF; ++k) {
        float wr[4];
#pragma unroll
        for (int q = 0; q < 4; ++q) wr[q] = w1[(size_t)k * HF + tid + 256 * q];
#pragma unroll
        for (int n = 0; n < TN2; ++n) {
            float xv = xs[n][k];
#pragma unroll
            for (int q = 0; q < 4; ++q) h[n][q] = fmaf(xv, wr[q], h[n][q]);
        }
    }
    float b1r[4], w2r[4];
#pragma unroll
    for (int q = 0; q < 4; ++q) { b1r[q] = b1[tid + 256 * q]; w2r[q] = w2[tid + 256 * q]; }
    for (int n = 0; n < TN2; ++n) {
        float s = 0.f;
#pragma unroll
        for (int q = 0; q < 4; ++q) {
            float hv = h[n][q] + b1r[q];
            s += (hv > 0.f ? hv : 0.f) * w2r[q];
        }
        part[tid] = s;
        __syncthreads();
        for (int off = 128; off > 0; off >>= 1) {
            if (tid < off) part[tid] += part[tid + off];
            __syncthreads();
        }
        if (tid == 0) zout[n0 + n] = part[0];
        __syncthreads();
    }
}

// -- Stage 2 (v18): v16 + replay instruction trim; v19: sums 4 z-planes ----
__global__ __launch_bounds__(512) void k_pers(
    const int* __restrict__ edges, const float* __restrict__ zbuf,
    const float* __restrict__ b2, float* __restrict__ dout /* [2][NTOT] */)
{
    const int bid = blockIdx.x;
    const int g = bid >> 1, sgn = bid & 1;
    const int tid = threadIdx.x;        // 0..511
    const int v = tid & 255, vh = tid >> 8;

    __shared__ float fv[NODES];
    __shared__ __align__(16) unsigned long long vkey[NODES];
    __shared__ int order_[NODES], rank_[NODES];
    __shared__ float fvr[NODES];
    __shared__ unsigned eks[EDGES];
    __shared__ int comp[NODES];
    __shared__ unsigned minE[NODES];
    __shared__ int nxt[NODES], par2[NODES];
    __shared__ unsigned char mstflag[EDGES];
    __shared__ int cnt, chg;
    __shared__ __align__(16) unsigned mstK[NODES];
    __shared__ unsigned srt[NODES];
    __shared__ int dr[NODES + 64];      // +64 dummy slots for branch-free write
    __shared__ int cmaxr[NODES];
    __shared__ int rkp[512];

    if (tid < 256) {
        float z0 = zbuf[g * NODES + tid] + zbuf[NTOT + g * NODES + tid]
                 + zbuf[2 * NTOT + g * NODES + tid] + zbuf[3 * NTOT + g * NODES + tid];
        float f0 = 1.f / (1.f + expf(-(z0 + b2[0])));
        fv[tid] = sgn ? -f0 : f0;
        vkey[tid] = ((unsigned long long)encf(fv[tid]) << 32) | (unsigned)tid;
        srt[tid] = INF32; dr[tid] = 0; cmaxr[tid] = 0;
        comp[tid] = tid;
    }
    __syncthreads();

    // split counting rank (vectorized): (v, vh) counts keys in 128-range
    {
        const unsigned long long mk = vkey[v];
        const int j0 = vh << 7;
        int c = 0;
#pragma unroll 8
        for (int j = j0; j < j0 + 128; j += 2) {
            ulonglong2 kk = *(const ulonglong2*)&vkey[j];
            c += (kk.x < mk) ? 1 : 0;
            c += (kk.y < mk) ? 1 : 0;
        }
        rkp[tid] = c;
    }
    __syncthreads();
    if (tid < 256) {
        int rk = rkp[tid] + rkp[tid + 256];
        order_[rk] = tid;
        rank_[tid] = rk;
        fvr[rk] = fv[tid];
    }
    __syncthreads();

    // edge keys in rank domain; self-loops -> INF (2 edges/thread)
#pragma unroll
    for (int q = 0; q < 2; ++q) {
        int e = tid + q * 512;
        int u = edges[2 * (g * EDGES + e)]     - g * NODES;
        int w = edges[2 * (g * EDGES + e) + 1] - g * NODES;
        if (u == w) { eks[e] = INF32; }
        else {
            int ra = rank_[u], rb = rank_[w];
            int rlo = ra < rb ? ra : rb, rhi = ra < rb ? rb : ra;
            eks[e] = ((unsigned)rhi << 18) | ((unsigned)e << 8) | (unsigned)rlo;
        }
        mstflag[e] = 0;
    }
    __syncthreads();

    // Boruvka with early exit, intra-comp pruning, convergence jumping
    for (int round = 0; round < 8; ++round) {
        if (tid < 256) minE[tid] = INF32;
        if (tid == 0) chg = 0;
        __syncthreads();
#pragma unroll
        for (int q = 0; q < 2; ++q) {
            int e = tid + q * 512;
            unsigned k = eks[e];
            if (k != INF32) {
                int rlo = (int)(k & 255u), rhi = (int)(k >> 18);
                int cu = comp[rlo], cv = comp[rhi];
                if (cu != cv) {
                    atomicMin(&minE[cu], k);
                    atomicMin(&minE[cv], k);
                } else if (!mstflag[e]) {
                    eks[e] = INF32;   // prune: never merges again
                }
            }
        }
        __syncthreads();
        if (tid < 256) {
            unsigned mk = minE[tid];
            int o = tid;
            if (mk != INF32) {
                int rlo = (int)(mk & 255u), rhi = (int)(mk >> 18);
                int cu = comp[rlo], cv = comp[rhi];
                o = (cu == tid) ? cv : cu;
                mstflag[(mk >> 8) & 0x3FFu] = 1;
                chg = 1;
            }
            nxt[tid] = o;
        }
        __syncthreads();
        if (!chg) break;
        if (tid < 256) {
            int o = nxt[tid];
            int p = o;
            if (nxt[o] == tid && tid < o) p = tid;
            par2[tid] = p;
        }
        __syncthreads();
        for (;;) {
            int p = par2[par2[v]];              // duplicated on both halves
            int done = __syncthreads_and(p == par2[v]);
            if (done) break;
            par2[v] = p;                        // benign same-value race
            __syncthreads();
        }
        if (tid < 256) comp[tid] = par2[comp[tid]];
        __syncthreads();
        // connected early-exit: single component => no merges remain
        if (__syncthreads_and(comp[v] == comp[0])) break;
    }

    // collect MST edges (<=255)
    if (tid == 0) cnt = 0;
    __syncthreads();
#pragma unroll
    for (int q = 0; q < 2; ++q) {
        int e = tid + q * 512;
        if (mstflag[e]) {
            int p = atomicAdd(&cnt, 1);
            mstK[p] = eks[e];
        }
    }
    __syncthreads();
    if (tid < 256 && tid >= cnt) mstK[tid] = INF32;
    __syncthreads();

    // split counting sort of MST keys (vectorized)
    {
        const unsigned m2 = mstK[v];
        const int j0 = vh << 7;
        int c = 0;
        if (m2 != INF32) {
#pragma unroll 8
            for (int j = j0; j < j0 + 128; j += 4) {
                uint4 kk = *(const uint4*)&mstK[j];
                c += (kk.x < m2) ? 1 : 0;
                c += (kk.y < m2) ? 1 : 0;
                c += (kk.z < m2) ? 1 : 0;
                c += (kk.w < m2) ? 1 : 0;
            }
        }
        rkp[tid] = c;
    }
    __syncthreads();
    if (tid < 256) {
        unsigned m2 = mstK[tid];
        if (m2 != INF32) srt[rkp[tid] + rkp[tid + 256]] = m2;
    }
    __syncthreads();

    // SWAR replay on wave 0 — deaths only (every edge merges)
    if (tid < 64) {
        const int ln = tid;
        unsigned rpack = (unsigned)ln * 0x01010101u + 0xC0804000u;
        int sv0 = (int)srt[ln], sv1 = (int)srt[ln + 64];
        int sv2 = (int)srt[ln + 128], sv3 = (int)srt[ln + 192];
        const int n = cnt;
        for (int blk = 0; blk < 4; ++blk) {
            const int base = blk << 6;
            if (base >= n) break;
            int lim = n - base; if (lim > 64) lim = 64;
            const int svb = blk == 0 ? sv0 : blk == 1 ? sv1 : blk == 2 ? sv2 : sv3;
            for (int sl = 0; sl < lim; ++sl) {
                const unsigned k = (unsigned)__builtin_amdgcn_readlane(svb, sl);
                const int lo = (int)(k & 255u);
                const int hi = (int)((k >> 18) & 255u);
                const unsigned va = (unsigned)__builtin_amdgcn_readlane((int)rpack, lo & 63);
                const int ca = (int)((va >> ((lo >> 6) << 3)) & 255u);
                const unsigned vb = (unsigned)__builtin_amdgcn_readlane((int)rpack, hi & 63);
                const int cb = (int)((vb >> ((hi >> 6) << 3)) & 255u);
                const int elder = ca < cb ? ca : cb;
                const int young = ca > cb ? ca : cb;
                // SWAR: replace bytes == young with elder (exact zero-detect)
                const unsigned y4 = (unsigned)young * 0x01010101u;
                const unsigned d4 = (unsigned)(young ^ elder) * 0x01010101u;
                const unsigned mm = rpack ^ y4;
                const unsigned ww = (mm | 0x80808080u) - 0x01010101u;
                const unsigned zm = ~(ww | mm) & 0x80808080u;
                rpack ^= d4 & ((zm >> 7) * 255u);
                // death: lane 0 writes dr[young]=hi, others hit dummy slots
                dr[(ln == 0) ? young : (NODES + ln)] = hi;
            }
        }
    }
    __syncthreads();

    // component max (extended persistence); comp[] = same partition as roots
    if (tid < 256) {
        atomicMax(&cmaxr[comp[tid]], tid);
    }
    __syncthreads();

    if (tid < 256) {
        const int db = dr[tid];
        float dv = (db != 0) ? fvr[db] : fvr[cmaxr[comp[tid]]];
        dout[sgn * NTOT + g * NODES + order_[tid]] = dv;
    }
}

// ------- Stage 3: per-pair MLPs + segment sum + linear head (fused) -------
__global__ __launch_bounds__(256) void k_head(
    const float* __restrict__ zbuf, const float* __restrict__ b2,
    const float* __restrict__ dbuf,
    const float* __restrict__ wp0, const float* __restrict__ bp0,
    const float* __restrict__ wp1, const float* __restrict__ bp1,
    const float* __restrict__ wh, const float* __restrict__ bh,
    float* __restrict__ out)
{
    const int g = blockIdx.x, tid = threadIdx.x;
    const int lane = tid & 63, wv = tid >> 6;
    __shared__ float lf[NODES], l0[NODES], l1[NODES];
    __shared__ float wpart[4][NC];
    {
        float z0 = zbuf[g * NODES + tid] + zbuf[NTOT + g * NODES + tid]
                 + zbuf[2 * NTOT + g * NODES + tid] + zbuf[3 * NTOT + g * NODES + tid];
        lf[tid] = 1.f / (1.f + expf(-(z0 + b2[0])));
    }
    l0[tid] = dbuf[g * NODES + tid];
    l1[tid] = dbuf[NTOT + g * NODES + tid];
    __syncthreads();
    const float w00 = wp0[tid], w01 = wp0[HP + tid], bb0 = bp0[tid];
    const float w10 = wp1[tid], w11 = wp1[HP + tid], bb1 = bp1[tid];
    float s0 = 0.f, s1 = 0.f;
    for (int n = 0; n < NODES; ++n) {
        float f = lf[n], d0 = l0[n], d1 = l1[n];
        float a0 = fmaf(f, w00, fmaf(d0, w01, bb0));      // h0 = (f, d_sub)
        float a1 = fmaf(-d1, w10, fmaf(f, w11, bb1));     // h1 = (-d_sup, f)
        s0 += a0 > 0.f ? a0 : 0.f;
        s1 += a1 > 0.f ? a1 : 0.f;
    }
    // parallel head: thread tid holds pooled phi0[tid], phi1[tid]
    float pc[NC];
    const float* whr0 = wh + (size_t)tid * NC;
    const float* whr1 = wh + (size_t)(HP + tid) * NC;
#pragma unroll
    for (int c = 0; c < NC; ++c) pc[c] = s0 * whr0[c] + s1 * whr1[c];
#pragma unroll
    for (int off = 32; off > 0; off >>= 1)
#pragma unroll
        for (int c = 0; c < NC; ++c) pc[c] += __shfl_xor(pc[c], off, 64);
    if (lane == 0)
#pragma unroll
        for (int c = 0; c < NC; ++c) wpart[wv][c] = pc[c];
    __syncthreads();
    if (tid < NC)
        out[g * NC + tid] = bh[tid] + wpart[0][tid] + wpart[1][tid]
                          + wpart[2][tid] + wpart[3][tid];
}

extern "C" void kernel_launch(void* const* d_in, const int* in_sizes, int n_in,
                              void* d_out, int out_size, void* d_ws, size_t ws_size,
                              hipStream_t stream)
{
    const float* x   = (const float*)d_in[0];
    const int*   edg = (const int*)d_in[1];
    const float* w1  = (const float*)d_in[3];
    const float* b1  = (const float*)d_in[4];
    const float* w2  = (const float*)d_in[5];
    const float* b2  = (const float*)d_in[6];
    const float* wp0 = (const float*)d_in[7];
    const float* bp0 = (const float*)d_in[8];
    const float* wp1 = (const float*)d_in[9];
    const float* bp1 = (const float*)d_in[10];
    const float* wh  = (const float*)d_in[11];
    const float* bh  = (const float*)d_in[12];

    float* zbuf = (float*)d_ws;                       // [4][NTOT] f32 partials
    float* dbuf = zbuf + 4 * NTOT;                    // [2][NTOT] f32
    unsigned short* w1f = (unsigned short*)(dbuf + 2 * NTOT);  // 1 MB bf16

    const size_t WS_REQ = (size_t)6 * NTOT * 4 + (size_t)HF * DF * 2 + 256;

    if (ws_size >= WS_REQ) {
        k_cvt_frag<<<256, 256, 0, stream>>>(w1, w1f);
        k_fil_mfma<<<1024, 256, 0, stream>>>(x, w1f, b1, w2, zbuf);
    } else {
        // fallback: plane 0 from k_fil, planes 1-3 zeroed
        hipMemsetAsync(zbuf + NTOT, 0, (size_t)3 * NTOT * 4, stream);
        k_fil     <<<NTOT / TN2, 256, 0, stream>>>(x, w1, b1, w2, zbuf);
    }
    k_pers<<<NUM_GRAPHS * 2, 512, 0, stream>>>(edg, zbuf, b2, dbuf);
    k_head<<<NUM_GRAPHS, 256, 0, stream>>>(zbuf, b2, dbuf, wp0, bp0, wp1, bp1,
                                           wh, bh, (float*)d_out);
}